// Round 8
// baseline (2587.832 us; speedup 1.0000x reference)
//
#include <hip/hip_runtime.h>

// Problem constants (from reference): N=4096, D=512, C=100, P=64
#define D 512
#define D4 128          // float4 chunks per row
#define P 64
#define NCHUNK 16       // 16 chunks x 8 float4 (32 floats) = D
#define SPB 8           // batch-stripes per class -> grid = C * SPB
#define PF 4            // proto pipeline depth (chunks in flight per thread)
#define EPS_COS 1e-8f
#define EPS_INV 1e-5f

__device__ __forceinline__ float wave_sum(float v) {
#pragma unroll
    for (int m = 32; m >= 1; m >>= 1) v += __shfl_xor(v, m, 64);
    return v;
}

__device__ __forceinline__ float dot4(const float4 a, const float4 b) {
    return a.x*b.x + a.y*b.y + a.z*b.z + a.w*b.w;
}

__device__ __forceinline__ void box_epilogue(
    float r_dot, float r_l1, float ff, float s_pp, int myp,
    float& prob_o, int& bidx_o)
{
    const float fnorm = fmaxf(sqrtf(ff),   EPS_COS);
    const float pnorm = fmaxf(sqrtf(s_pp), EPS_COS);
    const float d_cos = 1.0f - r_dot / (fnorm * pnorm);
    const float d_l1  = r_l1 * (1.0f / (float)D);
    const float d_l2  = (ff - 2.0f * r_dot + s_pp) * (1.0f / (float)D);

    float s[3];
    s[0] = 1.0f / (d_cos + EPS_INV);
    s[1] = 1.0f / (d_l1  + EPS_INV);
    s[2] = 1.0f / (d_l2  + EPS_INV);

    float prob = 0.f;
#pragma unroll
    for (int i = 0; i < 3; ++i) {
        float m = s[i];
#pragma unroll
        for (int w = 32; w >= 1; w >>= 1) m = fmaxf(m, __shfl_xor(m, w, 64));
        const float e = expf(s[i] - m);
        const float denom = wave_sum(e);
        prob += e / denom;
    }
    prob *= (1.0f / 3.0f);

    // argmax over protos, first-index tie-break
    float best = prob;
    int   bidx = myp;
#pragma unroll
    for (int w = 32; w >= 1; w >>= 1) {
        const float ov = __shfl_xor(best, w, 64);
        const int   oi = __shfl_xor(bidx, w, 64);
        if (ov > best || (ov == best && oi < bidx)) { best = ov; bidx = oi; }
    }
    prob_o = prob;
    bidx_o = bidx;
}

// ONE kernel, ONE dispatch. Block (c, s) self-discovers its boxes (no sort),
// then runs the chunked proto stream with:
//  - depth-4 register pipeline (8 loads/thread in flight; LDS write of chunk
//    c+1 uses registers loaded 3 iters earlier -> counted vmcnt, no drain)
//  - XOR-swizzled pbuf (store jj*64+(pp0^jj), read j*64+(lane^j)):
//    conflict-free ds_write AND ds_read (round 7: 4M conflict cycles)
__global__ __launch_bounds__(256) void fused_kernel(
    const float* __restrict__ feats,        // [N, D]
    const float* __restrict__ protos,       // [C, P, D]
    const int*   __restrict__ cls_ids,      // [N]
    const int*   __restrict__ proto_labels, // [C, P]
    float* __restrict__ out,                // [N] labels ++ [N, P] probs
    int N, int C)
{
    const int tid  = threadIdx.x;
    const int lane = tid & 63;
    const int w    = tid >> 6;

    // Bijective chunked XCD swizzle (m204)
    const int nbk = gridDim.x;
    const int q   = nbk >> 3, r = nbk & 7;
    const int xcd = blockIdx.x & 7, bix = blockIdx.x >> 3;
    const int id  = (xcd < r ? xcd * (q + 1) : r * (q + 1) + (xcd - r) * q) + bix;
    const int cls = id >> 3;                // SPB = 8
    const int s   = id & 7;
    if (cls >= C) return;

    __shared__ float4 pbuf[2 * 8 * P];      // 16 KB proto double-buffer
    __shared__ float4 fLds[8 * D4];         // 16 KB: 8 boxes' feats
    __shared__ int    sc[256];              // scan scratch
    __shared__ int    boxIds[512];          // local batches -> box id
    __shared__ float  ppLds[P];             // ||proto||^2

    // ---- setup: find this block's boxes (scan cls_ids, 16 KB) ----
    unsigned mask = 0;
    const int base = tid * 16;
    {
#pragma unroll
        for (int k = 0; k < 16; k += 4) {
            if (base + k + 3 < N) {
                const int4 v = *(const int4*)(cls_ids + base + k);
                if (v.x == cls) mask |= 1u << (k + 0);
                if (v.y == cls) mask |= 1u << (k + 1);
                if (v.z == cls) mask |= 1u << (k + 2);
                if (v.w == cls) mask |= 1u << (k + 3);
            } else {
                for (int kk = k; kk < k + 4; ++kk)
                    if (base + kk < N && cls_ids[base + kk] == cls)
                        mask |= 1u << kk;
            }
        }
    }
    const int cnt = __popc(mask);
    sc[tid] = cnt;
    boxIds[tid] = -1;
    boxIds[tid + 256] = -1;
    __syncthreads();
#pragma unroll
    for (int off = 1; off < 256; off <<= 1) {
        const int t = (tid >= off) ? sc[tid - off] : 0;
        __syncthreads();
        sc[tid] += t;
        __syncthreads();
    }
    const int myBase = sc[tid] - cnt;
    const int total  = sc[255];
    {
        int rk = myBase;
        unsigned m2 = mask;
        while (m2) {
            const int k = __ffs(m2) - 1; m2 &= m2 - 1;
            if (((rk >> 3) & 7) == s)
                boxIds[((rk >> 6) << 3) | (rk & 7)] = base + k;
            ++rk;
        }
    }
    __syncthreads();

    const int nb_total = (total + 7) >> 3;
    const int nLoc = (nb_total > s) ? (((nb_total - 1 - s) >> 3) + 1) : 0;
    if (nLoc == 0) return;                  // uniform exit

    const float*  prC    = protos + (size_t)cls * (P * D);
    const float4* feats4 = (const float4*)feats;
    const int jj  = tid & 7;                // f4-slot within chunk
    const int pp0 = tid >> 3;               // proto rows pp0, pp0+32
    const int st0 = jj * 64 + (pp0 ^ jj);           // swizzled store slots
    const int st1 = jj * 64 + ((pp0 + 32) ^ jj);

    float qq0 = 0.f, qq1 = 0.f;             // ||proto||^2 partials (L==0)

    for (int L = 0; L < nLoc; ++L) {
        const int sb    = L * 8;
        const int first = __builtin_amdgcn_readfirstlane(boxIds[sb]);
        const int k0    = __builtin_amdgcn_readfirstlane(boxIds[sb + 2 * w]);
        const int k1    = __builtin_amdgcn_readfirstlane(boxIds[sb + 2 * w + 1]);
        const int n0 = (k0 >= 0) ? k0 : first;
        const int n1 = (k1 >= 0) ? k1 : first;

        // 1) issue feat staging loads (4/thread, all in flight)
        float4 fr[4];
#pragma unroll
        for (int u = 0; u < 4; ++u) {
            const int i  = tid + 256 * u;
            int nb = boxIds[sb + (i >> 7)];
            if (nb < 0) nb = first;
            fr[u] = feats4[(size_t)nb * D4 + (i & 127)];
        }

        // 2) issue proto pipeline prologue: chunks 0..PF-1 (8 loads in flight)
        float4 pr0[PF], pr1[PF];
#pragma unroll
        for (int k = 0; k < PF; ++k) {
            pr0[k] = *(const float4*)(prC + (size_t)pp0 * D + k * 32 + jj * 4);
            pr1[k] = *(const float4*)(prC + (size_t)(pp0 + 32) * D + k * 32 + jj * 4);
        }

        // 3) feats -> LDS (lane-contiguous, conflict-free)
#pragma unroll
        for (int u = 0; u < 4; ++u) fLds[tid + 256 * u] = fr[u];

        // 4) chunk 0 -> pbuf[0] (swizzled store)
        if (L == 0) { qq0 += dot4(pr0[0], pr0[0]); qq1 += dot4(pr1[0], pr1[0]); }
        pbuf[st0] = pr0[0];
        pbuf[st1] = pr1[0];
        __syncthreads();

        // 5) feat self-norms from LDS (same order as before)
        float ffA, ffB;
        {
            const float4 a0 = fLds[(2 * w) * D4 + lane];
            const float4 a1 = fLds[(2 * w) * D4 + 64 + lane];
            ffA = wave_sum(dot4(a0, a0) + dot4(a1, a1));
            const float4 c0 = fLds[(2 * w + 1) * D4 + lane];
            const float4 c1 = fLds[(2 * w + 1) * D4 + 64 + lane];
            ffB = wave_sum(dot4(c0, c0) + dot4(c1, c1));
        }

        float dotA = 0.f, l1A = 0.f, dotB = 0.f, l1B = 0.f;

#pragma unroll
        for (int c = 0; c < NCHUNK; ++c) {
            // issue chunk c+PF into the slot freed by chunk c (static idx)
            if (c + PF < NCHUNK) {
                pr0[c % PF] = *(const float4*)(prC + (size_t)pp0 * D + (c + PF) * 32 + jj * 4);
                pr1[c % PF] = *(const float4*)(prC + (size_t)(pp0 + 32) * D + (c + PF) * 32 + jj * 4);
            }
            // write chunk c+1 (loaded PF-1 iters ago -> latency covered)
            if (c + 1 < NCHUNK) {
                const float4 w0 = pr0[(c + 1) % PF];
                const float4 w1 = pr1[(c + 1) % PF];
                if (L == 0) { qq0 += dot4(w0, w0); qq1 += dot4(w1, w1); }
                pbuf[((c + 1) & 1) * 512 + st0] = w0;
                pbuf[((c + 1) & 1) * 512 + st1] = w1;
            }
            // compute chunk c from pbuf[c&1] (swizzled read, conflict-free)
#pragma unroll
            for (int j = 0; j < 8; ++j) {
                const float4 qv = pbuf[(c & 1) * 512 + j * 64 + (lane ^ j)];
                const float4 av = fLds[(2 * w) * D4 + c * 8 + j];        // uniform
                const float4 bv = fLds[(2 * w + 1) * D4 + c * 8 + j];    // uniform
                float t;
                dotA += av.x*qv.x; t = av.x - qv.x; l1A += fabsf(t);
                dotA += av.y*qv.y; t = av.y - qv.y; l1A += fabsf(t);
                dotA += av.z*qv.z; t = av.z - qv.z; l1A += fabsf(t);
                dotA += av.w*qv.w; t = av.w - qv.w; l1A += fabsf(t);
                dotB += bv.x*qv.x; t = bv.x - qv.x; l1B += fabsf(t);
                dotB += bv.y*qv.y; t = bv.y - qv.y; l1B += fabsf(t);
                dotB += bv.z*qv.z; t = bv.z - qv.z; l1B += fabsf(t);
                dotB += bv.w*qv.w; t = bv.w - qv.w; l1B += fabsf(t);
            }
            __syncthreads();
        }

        if (L == 0) {
            // reduce qq over the 8 jj-threads sharing each proto row
#pragma unroll
            for (int m = 1; m <= 4; m <<= 1) {
                qq0 += __shfl_xor(qq0, m, 64);
                qq1 += __shfl_xor(qq1, m, 64);
            }
            if ((lane & 7) == 0) { ppLds[pp0] = qq0; ppLds[pp0 + 32] = qq1; }
            __syncthreads();
        }

        const float s_pp = ppLds[lane];     // lane p owns proto p

        float probA; int bidxA;
        box_epilogue(dotA, l1A, ffA, s_pp, lane, probA, bidxA);
        if (k0 >= 0) {
            out[(size_t)N + (size_t)n0 * P + lane] = probA;
            if (lane == 0) out[n0] = (float)proto_labels[cls * P + bidxA];
        }
        if (k1 >= 0) {
            float probB; int bidxB;
            box_epilogue(dotB, l1B, ffB, s_pp, lane, probB, bidxB);
            out[(size_t)N + (size_t)n1 * P + lane] = probB;
            if (lane == 0) out[n1] = (float)proto_labels[cls * P + bidxB];
        }
    }
}

extern "C" void kernel_launch(void* const* d_in, const int* in_sizes, int n_in,
                              void* d_out, int out_size, void* d_ws, size_t ws_size,
                              hipStream_t stream) {
    const float* feats        = (const float*)d_in[0];
    const float* protos       = (const float*)d_in[1];
    const int*   cls_ids      = (const int*)d_in[2];
    const int*   proto_labels = (const int*)d_in[3];
    float* out = (float*)d_out;

    const int N = in_sizes[2];                  // 4096
    const int C = in_sizes[1] / (D * P);        // 100

    fused_kernel<<<C * SPB, 256, 0, stream>>>(
        feats, protos, cls_ids, proto_labels, out, N, C);
}